// Round 2
// baseline (1689.112 us; speedup 1.0000x reference)
//
#include <hip/hip_runtime.h>

constexpr int Bn = 8;
constexpr int Mn = 8192;
constexpr int Pn = 256;
constexpr int Kn = 32;
constexpr float R2 = 0.09f;   // fp32(0.09) == jnp's weak-typed radius*radius cast

// =====================================================================
// Kernel 1: Voting module. 16 rows per block, 256 threads, fp32.
// =====================================================================
__global__ __launch_bounds__(256) void k_voting(
    const float* __restrict__ sxyz,   // (65536,2)
    const float* __restrict__ sfeat,  // (65536,256)
    const float* __restrict__ ow1, const float* __restrict__ ob1,
    const float* __restrict__ os1, const float* __restrict__ ot1,
    const float* __restrict__ ow2, const float* __restrict__ ob2,
    const float* __restrict__ fw1, const float* __restrict__ fb1,
    const float* __restrict__ fs1, const float* __restrict__ ft1,
    const float* __restrict__ fw2, const float* __restrict__ fb2,
    float* __restrict__ votes,        // (65536,2)
    float* __restrict__ vfeat)        // (65536,128)
{
  __shared__ float Xst[256][17];   // [c][r], pad 17 (odd) -> conflict-free writes
  __shared__ float Hst[256][17];   // [o][r]
  __shared__ float Wc[16][260];    // [k][o]

  const int tid = threadIdx.x;
  const int row0 = blockIdx.x * 16;

  for (int i = tid; i < 16 * 256; i += 256) {
    int r = i >> 8, c = i & 255;
    Xst[c][r] = sfeat[(row0 + r) * 256 + c];
  }
  __syncthreads();

  const int rg = tid >> 6;       // wave id 0..3 (wave-uniform)
  const int ro = rg * 4;
  const int cg = tid & 63;

  for (int br = 0; br < 2; ++br) {
    const float* w1 = br ? fw1 : ow1;
    const float* b1 = br ? fb1 : ob1;
    const float* s1 = br ? fs1 : os1;
    const float* t1 = br ? ft1 : ot1;

    float acc[4][4];
#pragma unroll
    for (int r = 0; r < 4; ++r)
#pragma unroll
      for (int j = 0; j < 4; ++j) acc[r][j] = 0.f;
    const int co = cg * 4;

    for (int kc = 0; kc < 16; ++kc) {
      __syncthreads();
      for (int i = tid; i < 256 * 16; i += 256) {
        int o = i >> 4, k = i & 15;
        Wc[k][o] = w1[o * 256 + kc * 16 + k];
      }
      __syncthreads();
#pragma unroll
      for (int k = 0; k < 16; ++k) {
        const int kk = kc * 16 + k;
        float x[4], w[4];
#pragma unroll
        for (int r = 0; r < 4; ++r) x[r] = Xst[kk][ro + r];
#pragma unroll
        for (int j = 0; j < 4; ++j) w[j] = Wc[k][co + j];
#pragma unroll
        for (int r = 0; r < 4; ++r)
#pragma unroll
          for (int j = 0; j < 4; ++j)
            acc[r][j] = fmaf(x[r], w[j], acc[r][j]);
      }
    }
    __syncthreads();
#pragma unroll
    for (int j = 0; j < 4; ++j) {
      int o = co + j;
      float bb = b1[o], ss = s1[o], tt = t1[o];
#pragma unroll
      for (int r = 0; r < 4; ++r)
        Hst[o][ro + r] = fmaxf((acc[r][j] + bb) * ss + tt, 0.f);
    }
    __syncthreads();

    if (br == 0) {
      // offsets: 16 rows x 2 outs, 32 threads, dot over 256
      if (tid < 32) {
        int r = tid >> 1, o = tid & 1;
        float a = 0.f;
        for (int k = 0; k < 256; ++k)
          a = fmaf(Hst[k][r], ow2[o * 256 + k], a);
        a += ob2[o];
        int row = row0 + r;
        votes[row * 2 + o] = sxyz[row * 2 + o] + a;
      }
    } else {
      // vote_feats: 16 rows x 128 outs, 4x2 tile per thread
      float a2[4][2];
#pragma unroll
      for (int r = 0; r < 4; ++r) { a2[r][0] = 0.f; a2[r][1] = 0.f; }
      const int co2 = cg * 2;
      for (int kc = 0; kc < 16; ++kc) {
        __syncthreads();
        for (int i = tid; i < 128 * 16; i += 256) {
          int o = i >> 4, k = i & 15;
          Wc[k][o] = fw2[o * 256 + kc * 16 + k];
        }
        __syncthreads();
#pragma unroll
        for (int k = 0; k < 16; ++k) {
          const int kk = kc * 16 + k;
          float x[4];
#pragma unroll
          for (int r = 0; r < 4; ++r) x[r] = Hst[kk][ro + r];
          float w0 = Wc[k][co2], w1v = Wc[k][co2 + 1];
#pragma unroll
          for (int r = 0; r < 4; ++r) {
            a2[r][0] = fmaf(x[r], w0, a2[r][0]);
            a2[r][1] = fmaf(x[r], w1v, a2[r][1]);
          }
        }
      }
      float bb0 = fb2[co2], bb1 = fb2[co2 + 1];
#pragma unroll
      for (int r = 0; r < 4; ++r) {
        int row = row0 + ro + r;
        vfeat[row * 128 + co2]     = a2[r][0] + bb0;
        vfeat[row * 128 + co2 + 1] = a2[r][1] + bb1;
      }
    }
  }
}

// =====================================================================
// Kernel 2: farthest point sampling. One block per batch, 256 threads,
// 32 points per thread. Tie-break lowest index (== jnp.argmax first-max).
// =====================================================================
__global__ __launch_bounds__(256) void k_fps(
    const float* __restrict__ votes,   // (8,8192,2)
    float* __restrict__ nxyz,          // (8,256,2) ws
    float* __restrict__ out)           // d_out new_xyz [0,4096)
{
  const int b = blockIdx.x, tid = threadIdx.x;
  const float* vb = votes + b * Mn * 2;
  float px[32], py[32], dist[32];
#pragma unroll
  for (int s = 0; s < 32; ++s) {
    int i = tid * 32 + s;
    px[s] = vb[i * 2];
    py[s] = vb[i * 2 + 1];
    dist[s] = 1e10f;
  }
  __shared__ float sd[4];
  __shared__ int si[4];
  __shared__ int sfar;
  if (tid == 0) {
    float nx = vb[0], ny = vb[1];
    nxyz[b * Pn * 2] = nx; nxyz[b * Pn * 2 + 1] = ny;
    out[b * Pn * 2] = nx;  out[b * Pn * 2 + 1] = ny;
  }
  int far = 0;
  for (int it = 1; it < Pn; ++it) {
    float cx = vb[far * 2], cy = vb[far * 2 + 1];
    float bd = -1.f; int bi = 0;
#pragma unroll
    for (int s = 0; s < 32; ++s) {
      float dx = px[s] - cx, dy = py[s] - cy;
      float d = fminf(dist[s], dx * dx + dy * dy);
      dist[s] = d;
      if (d > bd) { bd = d; bi = tid * 32 + s; }
    }
#pragma unroll
    for (int off = 32; off > 0; off >>= 1) {
      float od = __shfl_xor(bd, off);
      int oi = __shfl_xor(bi, off);
      if (od > bd || (od == bd && oi < bi)) { bd = od; bi = oi; }
    }
    if ((tid & 63) == 0) { sd[tid >> 6] = bd; si[tid >> 6] = bi; }
    __syncthreads();
    if (tid == 0) {
#pragma unroll
      for (int w = 1; w < 4; ++w)
        if (sd[w] > bd || (sd[w] == bd && si[w] < bi)) { bd = sd[w]; bi = si[w]; }
      sfar = bi;
      float nx = vb[bi * 2], ny = vb[bi * 2 + 1];
      nxyz[(b * Pn + it) * 2] = nx; nxyz[(b * Pn + it) * 2 + 1] = ny;
      out[(b * Pn + it) * 2] = nx;  out[(b * Pn + it) * 2 + 1] = ny;
    }
    __syncthreads();
    far = sfar;
  }
}

// =====================================================================
// Kernel 3: ball query = stable top-K=32 by (d2, idx); out-of-radius -> 0.
// One block per (b,p), 256 threads, 32 candidates each.
// =====================================================================
__global__ __launch_bounds__(256) void k_ballq(
    const float* __restrict__ votes, const float* __restrict__ nxyz,
    int* __restrict__ gidx)
{
  const int bp = blockIdx.x, tid = threadIdx.x;
  const int b = bp >> 8;
  const float* vb = votes + b * Mn * 2;
  const float sx = nxyz[bp * 2], sy = nxyz[bp * 2 + 1];
  const float a = sx * sx + sy * sy;
  float d2[32];
#pragma unroll
  for (int s = 0; s < 32; ++s) {
    int i = tid * 32 + s;
    float x = vb[i * 2], y = vb[i * 2 + 1];
    d2[s] = (a + (x * x + y * y)) - 2.f * (sx * x + sy * y);  // ref formula
  }
  __shared__ float sd[4];
  __shared__ int si[4];
  __shared__ int swi;
  unsigned mask = 0;
  for (int kk = 0; kk < Kn; ++kk) {
    float bd = 3.4e38f; int bi = 0x7fffffff;
#pragma unroll
    for (int s = 0; s < 32; ++s)
      if (!((mask >> s) & 1u) && d2[s] < bd) { bd = d2[s]; bi = tid * 32 + s; }
#pragma unroll
    for (int off = 32; off > 0; off >>= 1) {
      float od = __shfl_xor(bd, off);
      int oi = __shfl_xor(bi, off);
      if (od < bd || (od == bd && oi < bi)) { bd = od; bi = oi; }
    }
    if ((tid & 63) == 0) { sd[tid >> 6] = bd; si[tid >> 6] = bi; }
    __syncthreads();
    if (tid == 0) {
#pragma unroll
      for (int w = 1; w < 4; ++w)
        if (sd[w] < bd || (sd[w] == bd && si[w] < bi)) { bd = sd[w]; bi = si[w]; }
      swi = bi;
      gidx[bp * Kn + kk] = (bd > R2) ? 0 : bi;
    }
    __syncthreads();
    int wi = swi;
    if ((wi >> 5) == tid) mask |= 1u << (wi & 31);
  }
}

// =====================================================================
// Kernel 4: aggregation MLP (130->256->256) + max-pool over K=32.
// One block per (b,p), 256 threads, 4x8 register tile, fp32.
// LDS: combT 19008 + Hst 33792 + Wc 8320 + gix 128 = 61248 B (< 64 KB).
// =====================================================================
__global__ __launch_bounds__(256) void k_agg(
    const float* __restrict__ votes, const float* __restrict__ vfeat,
    const float* __restrict__ nxyz, const int* __restrict__ gidx,
    const float* __restrict__ aw1, const float* __restrict__ ab1,
    const float* __restrict__ as1, const float* __restrict__ at1,
    const float* __restrict__ aw2, const float* __restrict__ ab2,
    const float* __restrict__ as2, const float* __restrict__ at2,
    float* __restrict__ pooled)     // (2048,256)
{
  __shared__ float combT[144][33];   // [c][r], zero-pad c>=130; reused as Pool
  __shared__ float Hst[256][33];     // [o][r]
  __shared__ float Wc[8][260];       // [k][o]
  __shared__ int gix[32];
  float* Pool = &combT[0][0];        // [8][260] overlay, used after combT dead

  const int bp = blockIdx.x, tid = threadIdx.x;
  const int b = bp >> 8;
  if (tid < 32) gix[tid] = gidx[bp * 32 + tid];
  __syncthreads();
  const float sx = nxyz[bp * 2], sy = nxyz[bp * 2 + 1];

  for (int i = tid; i < 32 * 144; i += 256) {
    int r = i / 144, c = i % 144;
    float v = 0.f;
    if (c < 2)        v = votes[(b * Mn + gix[r]) * 2 + c] - (c ? sy : sx);
    else if (c < 130) v = vfeat[(b * Mn + gix[r]) * 128 + (c - 2)];
    combT[c][r] = v;
  }
  __syncthreads();

  const int rg = tid >> 5;      // 0..7
  const int ro = rg * 4;
  const int cg = tid & 31;
  const int co = cg * 8;

  // ---- layer 1: 130 -> 256 ----
  float acc[4][8];
#pragma unroll
  for (int r = 0; r < 4; ++r)
#pragma unroll
    for (int j = 0; j < 8; ++j) acc[r][j] = 0.f;

  for (int kc = 0; kc < 18; ++kc) {
    __syncthreads();
    for (int i = tid; i < 256 * 8; i += 256) {
      int o = i >> 3, k = i & 7;
      int c = kc * 8 + k;
      Wc[k][o] = (c < 130) ? aw1[o * 130 + c] : 0.f;
    }
    __syncthreads();
#pragma unroll
    for (int k = 0; k < 8; ++k) {
      const int kk = kc * 8 + k;
      float x[4], w[8];
#pragma unroll
      for (int r = 0; r < 4; ++r) x[r] = combT[kk][ro + r];
#pragma unroll
      for (int j = 0; j < 8; ++j) w[j] = Wc[k][co + j];
#pragma unroll
      for (int r = 0; r < 4; ++r)
#pragma unroll
        for (int j = 0; j < 8; ++j)
          acc[r][j] = fmaf(x[r], w[j], acc[r][j]);
    }
  }
  __syncthreads();
#pragma unroll
  for (int j = 0; j < 8; ++j) {
    int o = co + j;
    float bb = ab1[o], ss = as1[o], tt = at1[o];
#pragma unroll
    for (int r = 0; r < 4; ++r)
      Hst[o][ro + r] = fmaxf((acc[r][j] + bb) * ss + tt, 0.f);
  }
  __syncthreads();

  // ---- layer 2: 256 -> 256, then max-pool over rows ----
  float a2[4][8];
#pragma unroll
  for (int r = 0; r < 4; ++r)
#pragma unroll
    for (int j = 0; j < 8; ++j) a2[r][j] = 0.f;

  for (int kc = 0; kc < 32; ++kc) {
    __syncthreads();
    for (int i = tid; i < 256 * 8; i += 256) {
      int o = i >> 3, k = i & 7;
      Wc[k][o] = aw2[o * 256 + kc * 8 + k];
    }
    __syncthreads();
#pragma unroll
    for (int k = 0; k < 8; ++k) {
      const int kk = kc * 8 + k;
      float x[4], w[8];
#pragma unroll
      for (int r = 0; r < 4; ++r) x[r] = Hst[kk][ro + r];
#pragma unroll
      for (int j = 0; j < 8; ++j) w[j] = Wc[k][co + j];
#pragma unroll
      for (int r = 0; r < 4; ++r)
#pragma unroll
        for (int j = 0; j < 8; ++j)
          a2[r][j] = fmaf(x[r], w[j], a2[r][j]);
    }
  }
  __syncthreads();   // also makes combT (Pool overlay) safe to reuse
#pragma unroll
  for (int j = 0; j < 8; ++j) {
    int o = co + j;
    float bb = ab2[o], ss = as2[o], tt = at2[o];
    float m = -1.f;   // post-relu values are >= 0
#pragma unroll
    for (int r = 0; r < 4; ++r)
      m = fmaxf(m, fmaxf((a2[r][j] + bb) * ss + tt, 0.f));
    Pool[rg * 260 + o] = m;
  }
  __syncthreads();
  {
    float mx = Pool[tid];
#pragma unroll
    for (int w = 1; w < 8; ++w) mx = fmaxf(mx, Pool[w * 260 + tid]);
    pooled[bp * 256 + tid] = mx;
  }
}

// =====================================================================
// Kernel 5: proposal head (256->256->128->{1,10}). One block per (b,p).
// =====================================================================
__global__ __launch_bounds__(256) void k_head(
    const float* __restrict__ pooled,
    const float* __restrict__ pw1, const float* __restrict__ pb1,
    const float* __restrict__ ps1, const float* __restrict__ pt1,
    const float* __restrict__ pw2, const float* __restrict__ pb2,
    const float* __restrict__ ps2, const float* __restrict__ pt2,
    const float* __restrict__ objw, const float* __restrict__ objb,
    const float* __restrict__ clsw, const float* __restrict__ clsb,
    float* __restrict__ out)
{
  __shared__ float xr[256], y1[256], y2[128];
  const int bp = blockIdx.x, tid = threadIdx.x;
  xr[tid] = pooled[bp * 256 + tid];
  __syncthreads();
  {
    float a = 0.f;
    for (int c = 0; c < 256; ++c)
      a = fmaf(xr[c], pw1[tid * 256 + c], a);
    a = (a + pb1[tid]) * ps1[tid] + pt1[tid];
    y1[tid] = fmaxf(a, 0.f);
  }
  __syncthreads();
  if (tid < 128) {
    float a = 0.f;
    for (int c = 0; c < 256; ++c)
      a = fmaf(y1[c], pw2[tid * 256 + c], a);
    a = (a + pb2[tid]) * ps2[tid] + pt2[tid];
    y2[tid] = fmaxf(a, 0.f);
  }
  __syncthreads();
  if (tid < 10) {
    float a = 0.f;
    for (int c = 0; c < 128; ++c)
      a = fmaf(y2[c], clsw[tid * 128 + c], a);
    out[6144 + bp * 10 + tid] = a + clsb[tid];
  } else if (tid == 10) {
    float a = 0.f;
    for (int c = 0; c < 128; ++c)
      a = fmaf(y2[c], objw[c], a);
    out[4096 + bp] = a + objb[0];
  }
}

// =====================================================================
extern "C" void kernel_launch(void* const* d_in, const int* in_sizes, int n_in,
                              void* d_out, int out_size, void* d_ws, size_t ws_size,
                              hipStream_t stream)
{
  (void)in_sizes; (void)n_in; (void)out_size; (void)ws_size;
  const float* sxyz  = (const float*)d_in[0];
  const float* sfeat = (const float*)d_in[1];
  const float* ow1 = (const float*)d_in[2];
  const float* ob1 = (const float*)d_in[3];
  const float* os1 = (const float*)d_in[4];
  const float* ot1 = (const float*)d_in[5];
  const float* ow2 = (const float*)d_in[6];
  const float* ob2 = (const float*)d_in[7];
  const float* fw1 = (const float*)d_in[8];
  const float* fb1 = (const float*)d_in[9];
  const float* fs1 = (const float*)d_in[10];
  const float* ft1 = (const float*)d_in[11];
  const float* fw2 = (const float*)d_in[12];
  const float* fb2 = (const float*)d_in[13];
  const float* aw1 = (const float*)d_in[14];
  const float* ab1 = (const float*)d_in[15];
  const float* as1 = (const float*)d_in[16];
  const float* at1 = (const float*)d_in[17];
  const float* aw2 = (const float*)d_in[18];
  const float* ab2 = (const float*)d_in[19];
  const float* as2 = (const float*)d_in[20];
  const float* at2 = (const float*)d_in[21];
  const float* pw1 = (const float*)d_in[22];
  const float* pb1 = (const float*)d_in[23];
  const float* ps1 = (const float*)d_in[24];
  const float* pt1 = (const float*)d_in[25];
  const float* pw2 = (const float*)d_in[26];
  const float* pb2 = (const float*)d_in[27];
  const float* ps2 = (const float*)d_in[28];
  const float* pt2 = (const float*)d_in[29];
  const float* objw = (const float*)d_in[30];
  const float* objb = (const float*)d_in[31];
  const float* clsw = (const float*)d_in[32];
  const float* clsb = (const float*)d_in[33];

  char* ws = (char*)d_ws;
  float* votes  = (float*)(ws);                  //    524,288 B
  float* vfeat  = (float*)(ws + 524288);         // 33,554,432 B
  float* nxyz   = (float*)(ws + 34078720);       //     16,384 B
  int*   gidxp  = (int*)  (ws + 34095104);       //    262,144 B
  float* pooled = (float*)(ws + 34357248);       //  2,097,152 B  (end 36,454,400)
  float* out    = (float*)d_out;

  k_voting<<<dim3(4096), dim3(256), 0, stream>>>(
      sxyz, sfeat, ow1, ob1, os1, ot1, ow2, ob2,
      fw1, fb1, fs1, ft1, fw2, fb2, votes, vfeat);

  k_fps<<<dim3(8), dim3(256), 0, stream>>>(votes, nxyz, out);

  k_ballq<<<dim3(2048), dim3(256), 0, stream>>>(votes, nxyz, gidxp);

  k_agg<<<dim3(2048), dim3(256), 0, stream>>>(
      votes, vfeat, nxyz, gidxp,
      aw1, ab1, as1, at1, aw2, ab2, as2, at2, pooled);

  k_head<<<dim3(2048), dim3(256), 0, stream>>>(
      pooled, pw1, pb1, ps1, pt1, pw2, pb2, ps2, pt2,
      objw, objb, clsw, clsb, out);
}

// Round 7
// 1094.081 us; speedup vs baseline: 1.5439x; 1.5439x over previous
//
#include <hip/hip_runtime.h>

typedef __attribute__((ext_vector_type(8))) short bf16x8;
typedef __attribute__((ext_vector_type(4))) float f32x4;
typedef unsigned short u16;
typedef unsigned int u32;

#define DEV static __device__ __forceinline__
DEV u16 f2bf(float f) { u32 i = __float_as_uint(f); i += 0x7fffu + ((i >> 16) & 1u); return (u16)(i >> 16); }
DEV float bf2f(u16 u) { return __uint_as_float(((u32)u) << 16); }

constexpr int Mn = 8192;
constexpr int Pn = 256;
constexpr int Kn = 32;
constexpr float R2 = 0.09f;

// =====================================================================
// k_voting_off: round 2's proven k_voting, ft-branch deleted. The br=0
// (offsets/votes) path is byte-identical math: same LDS layout, same
// staging, same loop order, same epilogue -> bit-identical votes.
// =====================================================================
__global__ __launch_bounds__(256) void k_voting_off(
    const float* __restrict__ sxyz,   // (65536,2)
    const float* __restrict__ sfeat,  // (65536,256)
    const float* __restrict__ ow1, const float* __restrict__ ob1,
    const float* __restrict__ os1, const float* __restrict__ ot1,
    const float* __restrict__ ow2, const float* __restrict__ ob2,
    float* __restrict__ votes)        // (65536,2)
{
  __shared__ float Xst[256][17];
  __shared__ float Hst[256][17];
  __shared__ float Wc[16][260];

  const int tid = threadIdx.x;
  const int row0 = blockIdx.x * 16;

  for (int i = tid; i < 16 * 256; i += 256) {
    int r = i >> 8, c = i & 255;
    Xst[c][r] = sfeat[(row0 + r) * 256 + c];
  }
  __syncthreads();

  const int rg = tid >> 6;
  const int ro = rg * 4;
  const int cg = tid & 63;

  float acc[4][4];
#pragma unroll
  for (int r = 0; r < 4; ++r)
#pragma unroll
    for (int j = 0; j < 4; ++j) acc[r][j] = 0.f;
  const int co = cg * 4;

  for (int kc = 0; kc < 16; ++kc) {
    __syncthreads();
    for (int i = tid; i < 256 * 16; i += 256) {
      int o = i >> 4, k = i & 15;
      Wc[k][o] = ow1[o * 256 + kc * 16 + k];
    }
    __syncthreads();
#pragma unroll
    for (int k = 0; k < 16; ++k) {
      const int kk = kc * 16 + k;
      float x[4], w[4];
#pragma unroll
      for (int r = 0; r < 4; ++r) x[r] = Xst[kk][ro + r];
#pragma unroll
      for (int j = 0; j < 4; ++j) w[j] = Wc[k][co + j];
#pragma unroll
      for (int r = 0; r < 4; ++r)
#pragma unroll
        for (int j = 0; j < 4; ++j)
          acc[r][j] = fmaf(x[r], w[j], acc[r][j]);
    }
  }
  __syncthreads();
#pragma unroll
  for (int j = 0; j < 4; ++j) {
    int o = co + j;
    float bb = ob1[o], ss = os1[o], tt = ot1[o];
#pragma unroll
    for (int r = 0; r < 4; ++r)
      Hst[o][ro + r] = fmaxf((acc[r][j] + bb) * ss + tt, 0.f);
  }
  __syncthreads();

  if (tid < 32) {
    int r = tid >> 1, o = tid & 1;
    float a = 0.f;
    for (int k = 0; k < 256; ++k)
      a = fmaf(Hst[k][r], ow2[o * 256 + k], a);
    a += ob2[o];
    int row = row0 + r;
    votes[row * 2 + o] = sxyz[row * 2 + o] + a;
  }
}

// =====================================================================
// FPS — round 2 verbatim (proven).
// =====================================================================
__global__ __launch_bounds__(256) void k_fps(
    const float* __restrict__ votes, float* __restrict__ nxyz,
    float* __restrict__ out)
{
  const int b = blockIdx.x, tid = threadIdx.x;
  const float* vb = votes + b * Mn * 2;
  float px[32], py[32], dist[32];
#pragma unroll
  for (int s = 0; s < 32; ++s) {
    int i = tid * 32 + s;
    px[s] = vb[i * 2]; py[s] = vb[i * 2 + 1]; dist[s] = 1e10f;
  }
  __shared__ float sd[4];
  __shared__ int si[4];
  __shared__ int sfar;
  if (tid == 0) {
    float nx = vb[0], ny = vb[1];
    nxyz[b * Pn * 2] = nx; nxyz[b * Pn * 2 + 1] = ny;
    out[b * Pn * 2] = nx;  out[b * Pn * 2 + 1] = ny;
  }
  int far = 0;
  for (int it = 1; it < Pn; ++it) {
    float cx = vb[far * 2], cy = vb[far * 2 + 1];
    float bd = -1.f; int bi = 0;
#pragma unroll
    for (int s = 0; s < 32; ++s) {
      float dx = px[s] - cx, dy = py[s] - cy;
      float d = fminf(dist[s], dx * dx + dy * dy);
      dist[s] = d;
      if (d > bd) { bd = d; bi = tid * 32 + s; }
    }
#pragma unroll
    for (int off = 32; off > 0; off >>= 1) {
      float od = __shfl_xor(bd, off);
      int oi = __shfl_xor(bi, off);
      if (od > bd || (od == bd && oi < bi)) { bd = od; bi = oi; }
    }
    if ((tid & 63) == 0) { sd[tid >> 6] = bd; si[tid >> 6] = bi; }
    __syncthreads();
    if (tid == 0) {
#pragma unroll
      for (int w = 1; w < 4; ++w)
        if (sd[w] > bd || (sd[w] == bd && si[w] < bi)) { bd = sd[w]; bi = si[w]; }
      sfar = bi;
      float nx = vb[bi * 2], ny = vb[bi * 2 + 1];
      nxyz[(b * Pn + it) * 2] = nx; nxyz[(b * Pn + it) * 2 + 1] = ny;
      out[(b * Pn + it) * 2] = nx;  out[(b * Pn + it) * 2 + 1] = ny;
    }
    __syncthreads();
    far = sfar;
  }
}

// =====================================================================
// Ball query — round 2 verbatim (proven).
// =====================================================================
__global__ __launch_bounds__(256) void k_ballq(
    const float* __restrict__ votes, const float* __restrict__ nxyz,
    int* __restrict__ gidx)
{
  const int bp = blockIdx.x, tid = threadIdx.x;
  const int b = bp >> 8;
  const float* vb = votes + b * Mn * 2;
  const float sx = nxyz[bp * 2], sy = nxyz[bp * 2 + 1];
  const float a = sx * sx + sy * sy;
  float d2[32];
#pragma unroll
  for (int s = 0; s < 32; ++s) {
    int i = tid * 32 + s;
    float x = vb[i * 2], y = vb[i * 2 + 1];
    d2[s] = (a + (x * x + y * y)) - 2.f * (sx * x + sy * y);
  }
  __shared__ float sd[4];
  __shared__ int si[4];
  __shared__ int swi;
  unsigned mask = 0;
  for (int kk = 0; kk < Kn; ++kk) {
    float bd = 3.4e38f; int bi = 0x7fffffff;
#pragma unroll
    for (int s = 0; s < 32; ++s)
      if (!((mask >> s) & 1u) && d2[s] < bd) { bd = d2[s]; bi = tid * 32 + s; }
#pragma unroll
    for (int off = 32; off > 0; off >>= 1) {
      float od = __shfl_xor(bd, off);
      int oi = __shfl_xor(bi, off);
      if (od < bd || (od == bd && oi < bi)) { bd = od; bi = oi; }
    }
    if ((tid & 63) == 0) { sd[tid >> 6] = bd; si[tid >> 6] = bi; }
    __syncthreads();
    if (tid == 0) {
#pragma unroll
      for (int w = 1; w < 4; ++w)
        if (sd[w] < bd || (sd[w] == bd && si[w] < bi)) { bd = sd[w]; bi = si[w]; }
      swi = bi;
      gidx[bp * Kn + kk] = (bd > R2) ? 0 : bi;
    }
    __syncthreads();
    int wi = swi;
    if ((wi >> 5) == tid) mask |= 1u << (wi & 31);
  }
}

// =====================================================================
// Prep: bf16 weight conversions (runs AFTER the discrete path).
// =====================================================================
__global__ __launch_bounds__(256) void k_prep(
    const float* __restrict__ fw1, const float* __restrict__ fw2,
    const float* __restrict__ aw1, const float* __restrict__ aw2,
    u16* __restrict__ FW1h, u16* __restrict__ FW2b,
    u16* __restrict__ AW1b, u16* __restrict__ AW2b)
{
  const int gid = blockIdx.x * 256 + threadIdx.x;
  const int gsz = gridDim.x * 256;
  for (int i = gid; i < 65536; i += gsz) FW1h[i] = f2bf(fw1[i]);
  for (int i = gid; i < 32768; i += gsz) FW2b[i] = f2bf(fw2[i]);
  for (int i = gid; i < 65536; i += gsz) AW2b[i] = f2bf(aw2[i]);
  for (int i = gid; i < 49152; i += gsz) {
    int o = i / 192, k = i % 192;
    AW1b[i] = (k < 130) ? f2bf(aw1[o * 130 + k]) : (u16)0;
  }
}

// =====================================================================
// k_vf: fused ft-branch. vf = relu_affine(sfeat@fw1^T) @ fw2^T + fb2.
// =====================================================================
__global__ __launch_bounds__(256) void k_vf(
    const float* __restrict__ sfeat, const u16* __restrict__ FW1h,
    const float* __restrict__ fb1, const float* __restrict__ fs1,
    const float* __restrict__ ft1, const u16* __restrict__ FW2b,
    const float* __restrict__ fb2, u16* __restrict__ vfeat)
{
  __shared__ u16 Hs[128 * 136];
  __shared__ u16 As[128 * 40];
  __shared__ u16 Bs[128 * 40];
  const int tid = threadIdx.x;
  const int row0 = blockIdx.x * 128;
  const int wid = tid >> 6, lane = tid & 63, m16 = lane & 15, quad = lane >> 4;
  const int wr = wid >> 1, wc = wid & 1;
  const int sr = tid >> 1, sk = (tid & 1) * 16;

  f32x4 acc2[4][4];
#pragma unroll
  for (int mt = 0; mt < 4; ++mt)
#pragma unroll
    for (int nt = 0; nt < 4; ++nt) acc2[mt][nt] = (f32x4){0.f, 0.f, 0.f, 0.f};

  for (int h = 0; h < 2; ++h) {
    f32x4 acc[4][4];
#pragma unroll
    for (int mt = 0; mt < 4; ++mt)
#pragma unroll
      for (int nt = 0; nt < 4; ++nt) acc[mt][nt] = (f32x4){0.f, 0.f, 0.f, 0.f};

    for (int s = 0; s < 8; ++s) {
      __syncthreads();
      {
        const float* src = &sfeat[(row0 + sr) * 256 + s * 32 + sk];
        u32 packed[8];
#pragma unroll
        for (int q = 0; q < 4; ++q) {
          float4 v = *(const float4*)&src[q * 4];
          packed[q * 2]     = (u32)f2bf(v.x) | ((u32)f2bf(v.y) << 16);
          packed[q * 2 + 1] = (u32)f2bf(v.z) | ((u32)f2bf(v.w) << 16);
        }
        *(uint4*)&As[sr * 40 + sk]     = *(uint4*)&packed[0];
        *(uint4*)&As[sr * 40 + sk + 8] = *(uint4*)&packed[4];
        const u16* bsrc = &FW1h[(h * 128 + sr) * 256 + s * 32 + sk];
        *(uint4*)&Bs[sr * 40 + sk]     = *(const uint4*)&bsrc[0];
        *(uint4*)&Bs[sr * 40 + sk + 8] = *(const uint4*)&bsrc[8];
      }
      __syncthreads();
#pragma unroll
      for (int mt = 0; mt < 4; ++mt) {
        bf16x8 af = *(const bf16x8*)&As[(wr * 64 + mt * 16 + m16) * 40 + quad * 8];
#pragma unroll
        for (int nt = 0; nt < 4; ++nt) {
          bf16x8 bfr = *(const bf16x8*)&Bs[(wc * 64 + nt * 16 + m16) * 40 + quad * 8];
          acc[mt][nt] = __builtin_amdgcn_mfma_f32_16x16x32_bf16(af, bfr, acc[mt][nt], 0, 0, 0);
        }
      }
    }
    __syncthreads();
#pragma unroll
    for (int nt = 0; nt < 4; ++nt) {
      int colL = wc * 64 + nt * 16 + m16;
      int col = h * 128 + colL;
      float bb = fb1[col], ss = fs1[col], tt = ft1[col];
#pragma unroll
      for (int mt = 0; mt < 4; ++mt) {
        int rL = wr * 64 + mt * 16 + quad * 4;
#pragma unroll
        for (int r = 0; r < 4; ++r)
          Hs[(rL + r) * 136 + colL] = f2bf(fmaxf((acc[mt][nt][r] + bb) * ss + tt, 0.f));
      }
    }
    for (int s2 = 0; s2 < 4; ++s2) {
      __syncthreads();
      {
        const u16* bsrc = &FW2b[sr * 256 + h * 128 + s2 * 32 + sk];
        *(uint4*)&Bs[sr * 40 + sk]     = *(const uint4*)&bsrc[0];
        *(uint4*)&Bs[sr * 40 + sk + 8] = *(const uint4*)&bsrc[8];
      }
      __syncthreads();
#pragma unroll
      for (int mt = 0; mt < 4; ++mt) {
        bf16x8 af = *(const bf16x8*)&Hs[(wr * 64 + mt * 16 + m16) * 136 + s2 * 32 + quad * 8];
#pragma unroll
        for (int nt = 0; nt < 4; ++nt) {
          bf16x8 bfr = *(const bf16x8*)&Bs[(wc * 64 + nt * 16 + m16) * 40 + quad * 8];
          acc2[mt][nt] = __builtin_amdgcn_mfma_f32_16x16x32_bf16(af, bfr, acc2[mt][nt], 0, 0, 0);
        }
      }
    }
  }
#pragma unroll
  for (int nt = 0; nt < 4; ++nt) {
    int col = wc * 64 + nt * 16 + m16;
    float bb = fb2[col];
#pragma unroll
    for (int mt = 0; mt < 4; ++mt) {
      int rbase = row0 + wr * 64 + mt * 16 + quad * 4;
#pragma unroll
      for (int r = 0; r < 4; ++r)
        vfeat[(rbase + r) * 128 + col] = f2bf(acc2[mt][nt][r] + bb);
    }
  }
}

// =====================================================================
// k_agg: gather vf -> comb (K=130 pad 192) -> MFMA1 -> affine/relu ->
// MFMA2 (K=256) -> affine/relu -> max-pool over 32 samples.
// =====================================================================
__global__ __launch_bounds__(256) void k_agg(
    const float* __restrict__ votes, const u16* __restrict__ vfeat,
    const float* __restrict__ nxyz, const int* __restrict__ gidx,
    const u16* __restrict__ AW1b, const float* __restrict__ ab1,
    const float* __restrict__ as1, const float* __restrict__ at1,
    const u16* __restrict__ AW2b, const float* __restrict__ ab2,
    const float* __restrict__ as2, const float* __restrict__ at2,
    float* __restrict__ pooled)
{
  __shared__ u16 U[32 * 264];      // CombA (stride 200) then As (stride 264)
  __shared__ u16 Bs[256 * 72];     // B staging; x2T alias
  __shared__ int gix[32];
  __shared__ float gvx[32], gvy[32];
  u16* CombA = U;
  u16* As = U;
  float* x2T = (float*)Bs;

  const int bp = blockIdx.x, tid = threadIdx.x, b = bp >> 8;
  if (tid < 32) {
    int g = gidx[bp * 32 + tid];
    gix[tid] = g;
    gvx[tid] = votes[(b * Mn + g) * 2];
    gvy[tid] = votes[(b * Mn + g) * 2 + 1];
  }
  __syncthreads();
  const float sx = nxyz[bp * 2], sy = nxyz[bp * 2 + 1];

  if (tid < 192) {
    int row = tid / 6, c = tid % 6;
    const u16* vsrc = &vfeat[(b * Mn + gix[row]) * 128];
    u16* dst = &CombA[row * 200 + c * 32];
    if (c == 0) {
      dst[0] = f2bf(gvx[row] - sx);
      dst[1] = f2bf(gvy[row] - sy);
      for (int k = 2; k < 32; ++k) dst[k] = vsrc[k - 2];
    } else if (c <= 3) {
      for (int k = 0; k < 32; ++k) dst[k] = vsrc[c * 32 + k - 2];
    } else if (c == 4) {
      dst[0] = vsrc[126]; dst[1] = vsrc[127];
      for (int k = 2; k < 32; ++k) dst[k] = 0;
    } else {
      for (int k = 0; k < 32; ++k) dst[k] = 0;
    }
  }

  const int wid = tid >> 6, lane = tid & 63, m16 = lane & 15, quad = lane >> 4;
  const int mt = wid & 1, nh = wid >> 1;

  // ---- MFMA1: x1 = comb @ aw1^T (K=192 incl. zero-pad) ----
  f32x4 acc[8];
#pragma unroll
  for (int nt = 0; nt < 8; ++nt) acc[nt] = (f32x4){0.f, 0.f, 0.f, 0.f};
  for (int s = 0; s < 3; ++s) {
    __syncthreads();
    for (int i = tid; i < 4096; i += 256) {
      int n = i >> 4, c4 = i & 15;
      *(uint2*)&Bs[n * 72 + c4 * 4] = *(const uint2*)&AW1b[n * 192 + s * 64 + c4 * 4];
    }
    __syncthreads();
#pragma unroll
    for (int ks = 0; ks < 2; ++ks) {
      bf16x8 af = *(const bf16x8*)&CombA[(mt * 16 + m16) * 200 + s * 64 + ks * 32 + quad * 8];
#pragma unroll
      for (int nt = 0; nt < 8; ++nt) {
        bf16x8 bf_ = *(const bf16x8*)&Bs[(nh * 128 + nt * 16 + m16) * 72 + ks * 32 + quad * 8];
        acc[nt] = __builtin_amdgcn_mfma_f32_16x16x32_bf16(af, bf_, acc[nt], 0, 0, 0);
      }
    }
  }
  __syncthreads();
#pragma unroll
  for (int nt = 0; nt < 8; ++nt) {
    int col = nh * 128 + nt * 16 + m16;
    float bb = ab1[col], ss = as1[col], tt = at1[col];
#pragma unroll
    for (int r = 0; r < 4; ++r) {
      int samp = mt * 16 + quad * 4 + r;
      As[samp * 264 + col] = f2bf(fmaxf((acc[nt][r] + bb) * ss + tt, 0.f));
    }
  }

  // ---- MFMA2: x2 = x1 @ aw2^T (K=256) ----
  f32x4 acc2[8];
#pragma unroll
  for (int nt = 0; nt < 8; ++nt) acc2[nt] = (f32x4){0.f, 0.f, 0.f, 0.f};
  for (int s = 0; s < 4; ++s) {
    __syncthreads();
    for (int i = tid; i < 4096; i += 256) {
      int n = i >> 4, c4 = i & 15;
      *(uint2*)&Bs[n * 72 + c4 * 4] = *(const uint2*)&AW2b[n * 256 + s * 64 + c4 * 4];
    }
    __syncthreads();
#pragma unroll
    for (int ks = 0; ks < 2; ++ks) {
      bf16x8 af = *(const bf16x8*)&As[(mt * 16 + m16) * 264 + s * 64 + ks * 32 + quad * 8];
#pragma unroll
      for (int nt = 0; nt < 8; ++nt) {
        bf16x8 bf_ = *(const bf16x8*)&Bs[(nh * 128 + nt * 16 + m16) * 72 + ks * 32 + quad * 8];
        acc2[nt] = __builtin_amdgcn_mfma_f32_16x16x32_bf16(af, bf_, acc2[nt], 0, 0, 0);
      }
    }
  }
  __syncthreads();
#pragma unroll
  for (int nt = 0; nt < 8; ++nt) {
    int col = nh * 128 + nt * 16 + m16;
    float bb = ab2[col], ss = as2[col], tt = at2[col];
#pragma unroll
    for (int r = 0; r < 4; ++r) {
      int samp = mt * 16 + quad * 4 + r;
      x2T[col * 33 + samp] = fmaxf((acc2[nt][r] + bb) * ss + tt, 0.f);
    }
  }
  __syncthreads();
  {
    float m = x2T[tid * 33];
#pragma unroll
    for (int s2 = 1; s2 < 32; ++s2) m = fmaxf(m, x2T[tid * 33 + s2]);
    pooled[bp * 256 + tid] = m;
  }
}

// =====================================================================
// Proposal head — round 2 verbatim (proven).
// =====================================================================
__global__ __launch_bounds__(256) void k_head(
    const float* __restrict__ pooled,
    const float* __restrict__ pw1, const float* __restrict__ pb1,
    const float* __restrict__ ps1, const float* __restrict__ pt1,
    const float* __restrict__ pw2, const float* __restrict__ pb2,
    const float* __restrict__ ps2, const float* __restrict__ pt2,
    const float* __restrict__ objw, const float* __restrict__ objb,
    const float* __restrict__ clsw, const float* __restrict__ clsb,
    float* __restrict__ out)
{
  __shared__ float xr[256], y1[256], y2[128];
  const int bp = blockIdx.x, tid = threadIdx.x;
  xr[tid] = pooled[bp * 256 + tid];
  __syncthreads();
  {
    float a = 0.f;
    for (int c = 0; c < 256; ++c) a = fmaf(xr[c], pw1[tid * 256 + c], a);
    a = (a + pb1[tid]) * ps1[tid] + pt1[tid];
    y1[tid] = fmaxf(a, 0.f);
  }
  __syncthreads();
  if (tid < 128) {
    float a = 0.f;
    for (int c = 0; c < 256; ++c) a = fmaf(y1[c], pw2[tid * 256 + c], a);
    a = (a + pb2[tid]) * ps2[tid] + pt2[tid];
    y2[tid] = fmaxf(a, 0.f);
  }
  __syncthreads();
  if (tid < 10) {
    float a = 0.f;
    for (int c = 0; c < 128; ++c) a = fmaf(y2[c], clsw[tid * 128 + c], a);
    out[6144 + bp * 10 + tid] = a + clsb[tid];
  } else if (tid == 10) {
    float a = 0.f;
    for (int c = 0; c < 128; ++c) a = fmaf(y2[c], objw[c], a);
    out[4096 + bp] = a + objb[0];
  }
}

// =====================================================================
extern "C" void kernel_launch(void* const* d_in, const int* in_sizes, int n_in,
                              void* d_out, int out_size, void* d_ws, size_t ws_size,
                              hipStream_t stream)
{
  (void)in_sizes; (void)n_in; (void)out_size; (void)ws_size;
  const float* sxyz  = (const float*)d_in[0];
  const float* sfeat = (const float*)d_in[1];
  const float* ow1 = (const float*)d_in[2];
  const float* ob1 = (const float*)d_in[3];
  const float* os1 = (const float*)d_in[4];
  const float* ot1 = (const float*)d_in[5];
  const float* ow2 = (const float*)d_in[6];
  const float* ob2 = (const float*)d_in[7];
  const float* fw1 = (const float*)d_in[8];
  const float* fb1 = (const float*)d_in[9];
  const float* fs1 = (const float*)d_in[10];
  const float* ft1 = (const float*)d_in[11];
  const float* fw2 = (const float*)d_in[12];
  const float* fb2 = (const float*)d_in[13];
  const float* aw1 = (const float*)d_in[14];
  const float* ab1 = (const float*)d_in[15];
  const float* as1 = (const float*)d_in[16];
  const float* at1 = (const float*)d_in[17];
  const float* aw2 = (const float*)d_in[18];
  const float* ab2 = (const float*)d_in[19];
  const float* as2 = (const float*)d_in[20];
  const float* at2 = (const float*)d_in[21];
  const float* pw1 = (const float*)d_in[22];
  const float* pb1 = (const float*)d_in[23];
  const float* ps1 = (const float*)d_in[24];
  const float* pt1 = (const float*)d_in[25];
  const float* pw2 = (const float*)d_in[26];
  const float* pb2 = (const float*)d_in[27];
  const float* ps2 = (const float*)d_in[28];
  const float* pt2 = (const float*)d_in[29];
  const float* objw = (const float*)d_in[30];
  const float* objb = (const float*)d_in[31];
  const float* clsw = (const float*)d_in[32];
  const float* clsb = (const float*)d_in[33];

  // ws budget: 20,103,168 B (round-2 proved >= 36,454,400 is safe)
  char* ws = (char*)d_ws;
  float* votes  = (float*)(ws + 0);             //    524,288
  u16*   vfeat  = (u16*)  (ws + 524288);        // 16,777,216
  float* nxyz   = (float*)(ws + 17301504);      //     16,384
  int*   gidxp  = (int*)  (ws + 17317888);      //    262,144
  float* pooled = (float*)(ws + 17580032);      //  2,097,152
  u16*   FW1h   = (u16*)  (ws + 19677184);      //    131,072
  u16*   FW2b   = (u16*)  (ws + 19808256);      //     65,536
  u16*   AW1b   = (u16*)  (ws + 19873792);      //     98,304
  u16*   AW2b   = (u16*)  (ws + 19972096);      //    131,072
  float* out    = (float*)d_out;

  // Discrete path FIRST (all round-2-proven kernels), so output 0 is
  // written before any unproven kernel runs.
  k_voting_off<<<dim3(4096), dim3(256), 0, stream>>>(
      sxyz, sfeat, ow1, ob1, os1, ot1, ow2, ob2, votes);

  k_fps<<<dim3(8), dim3(256), 0, stream>>>(votes, nxyz, out);

  k_ballq<<<dim3(2048), dim3(256), 0, stream>>>(votes, nxyz, gidxp);

  // Feature path (unproven kernels) AFTER output-0 writes.
  k_prep<<<dim3(256), dim3(256), 0, stream>>>(
      fw1, fw2, aw1, aw2, FW1h, FW2b, AW1b, AW2b);

  k_vf<<<dim3(512), dim3(256), 0, stream>>>(
      sfeat, FW1h, fb1, fs1, ft1, FW2b, fb2, vfeat);

  k_agg<<<dim3(2048), dim3(256), 0, stream>>>(
      votes, vfeat, nxyz, gidxp, AW1b, ab1, as1, at1,
      AW2b, ab2, as2, at2, pooled);

  k_head<<<dim3(2048), dim3(256), 0, stream>>>(
      pooled, pw1, pb1, ps1, pt1, pw2, pb2, ps2, pt2,
      objw, objb, clsw, clsb, out);
}

// Round 8
// 1025.278 us; speedup vs baseline: 1.6475x; 1.0671x over previous
//
#include <hip/hip_runtime.h>

typedef __attribute__((ext_vector_type(8))) short bf16x8;
typedef __attribute__((ext_vector_type(4))) float f32x4;
typedef unsigned short u16;
typedef unsigned int u32;
typedef unsigned long long u64;

#define DEV static __device__ __forceinline__
DEV u16 f2bf(float f) { u32 i = __float_as_uint(f); i += 0x7fffu + ((i >> 16) & 1u); return (u16)(i >> 16); }
DEV float bf2f(u16 u) { return __uint_as_float(((u32)u) << 16); }

constexpr int Mn = 8192;
constexpr int Pn = 256;
constexpr int Kn = 32;
constexpr float R2 = 0.09f;

// =====================================================================
// k_voting_off — round 7 verbatim (proven; produces bit-exact votes).
// =====================================================================
__global__ __launch_bounds__(256) void k_voting_off(
    const float* __restrict__ sxyz,   // (65536,2)
    const float* __restrict__ sfeat,  // (65536,256)
    const float* __restrict__ ow1, const float* __restrict__ ob1,
    const float* __restrict__ os1, const float* __restrict__ ot1,
    const float* __restrict__ ow2, const float* __restrict__ ob2,
    float* __restrict__ votes)        // (65536,2)
{
  __shared__ float Xst[256][17];
  __shared__ float Hst[256][17];
  __shared__ float Wc[16][260];

  const int tid = threadIdx.x;
  const int row0 = blockIdx.x * 16;

  for (int i = tid; i < 16 * 256; i += 256) {
    int r = i >> 8, c = i & 255;
    Xst[c][r] = sfeat[(row0 + r) * 256 + c];
  }
  __syncthreads();

  const int rg = tid >> 6;
  const int ro = rg * 4;
  const int cg = tid & 63;

  float acc[4][4];
#pragma unroll
  for (int r = 0; r < 4; ++r)
#pragma unroll
    for (int j = 0; j < 4; ++j) acc[r][j] = 0.f;
  const int co = cg * 4;

  for (int kc = 0; kc < 16; ++kc) {
    __syncthreads();
    for (int i = tid; i < 256 * 16; i += 256) {
      int o = i >> 4, k = i & 15;
      Wc[k][o] = ow1[o * 256 + kc * 16 + k];
    }
    __syncthreads();
#pragma unroll
    for (int k = 0; k < 16; ++k) {
      const int kk = kc * 16 + k;
      float x[4], w[4];
#pragma unroll
      for (int r = 0; r < 4; ++r) x[r] = Xst[kk][ro + r];
#pragma unroll
      for (int j = 0; j < 4; ++j) w[j] = Wc[k][co + j];
#pragma unroll
      for (int r = 0; r < 4; ++r)
#pragma unroll
        for (int j = 0; j < 4; ++j)
          acc[r][j] = fmaf(x[r], w[j], acc[r][j]);
    }
  }
  __syncthreads();
#pragma unroll
  for (int j = 0; j < 4; ++j) {
    int o = co + j;
    float bb = ob1[o], ss = os1[o], tt = ot1[o];
#pragma unroll
    for (int r = 0; r < 4; ++r)
      Hst[o][ro + r] = fmaxf((acc[r][j] + bb) * ss + tt, 0.f);
  }
  __syncthreads();

  if (tid < 32) {
    int r = tid >> 1, o = tid & 1;
    float a = 0.f;
    for (int k = 0; k < 256; ++k)
      a = fmaf(Hst[k][r], ow2[o * 256 + k], a);
    a += ob2[o];
    int row = row0 + r;
    votes[row * 2 + o] = sxyz[row * 2 + o] + a;
  }
}

// =====================================================================
// k_fps v2 — latency-optimized. Decisions bit-identical to round 7:
// same per-thread scan expressions; cross-lane/cross-wave combine uses
// the same (dist desc, idx asc) total order, packed as u64
// (floatbits(d)<<32 | ~idx) so max() == argmax-with-lowest-index-tie.
// Winner coords ride the butterfly (no dependent global loads); one
// barrier/iter via double-buffered slots; history in LDS; bulk writes.
// =====================================================================
__global__ __launch_bounds__(256) void k_fps(
    const float* __restrict__ votes, float* __restrict__ nxyz,
    float* __restrict__ out)
{
  const int b = blockIdx.x, tid = threadIdx.x;
  const float* vb = votes + b * Mn * 2;
  __shared__ u64 slotp[2][4];
  __shared__ float slotx[2][4], sloty[2][4];
  __shared__ float histx[256], histy[256];

  float px[32], py[32], dist[32];
#pragma unroll
  for (int s = 0; s < 32; ++s) {
    int i = tid * 32 + s;
    float2 p = *(const float2*)&vb[i * 2];
    px[s] = p.x; py[s] = p.y; dist[s] = 1e10f;
  }
  float cx = vb[0], cy = vb[1];
  if (tid == 0) { histx[0] = cx; histy[0] = cy; }

  for (int it = 1; it < Pn; ++it) {
    // per-thread scan — identical expressions/order to round 7
    float bd = -1.f; int bi = 0;
#pragma unroll
    for (int s = 0; s < 32; ++s) {
      float dx = px[s] - cx, dy = py[s] - cy;
      float d = fminf(dist[s], dx * dx + dy * dy);
      dist[s] = d;
      if (d > bd) { bd = d; bi = tid * 32 + s; }
    }
    // pack: max(pk) == (max d, then min idx)
    u64 pk = ((u64)__float_as_uint(bd) << 32) | (u32)(~bi);
    float wx = px[bi & 31], wy = py[bi & 31];  // bi&31 == s of winner (bi = tid*32+s)
    // NOTE: bi&31 is a compile-time-unknown register index; avoid it:
    // recompute winner coords via second scan-free trick is costly, so
    // instead carry coords by re-selecting during the scan:
    // (handled below — see wsel scan)
    (void)wx; (void)wy;
    // re-derive winner coords with a tiny select chain (s-indexed regs):
    float cxw = px[0], cyw = py[0];
#pragma unroll
    for (int s = 0; s < 32; ++s) {
      bool win = (tid * 32 + s) == bi;
      cxw = win ? px[s] : cxw;
      cyw = win ? py[s] : cyw;
    }
    // wave butterfly: carry (pk, x, y)
#pragma unroll
    for (int off = 32; off > 0; off >>= 1) {
      u64 opk = __shfl_xor(pk, off);
      float ox = __shfl_xor(cxw, off);
      float oy = __shfl_xor(cyw, off);
      if (opk > pk) { pk = opk; cxw = ox; cyw = oy; }
    }
    const int buf = it & 1, wv = tid >> 6;
    if ((tid & 63) == 0) {
      slotp[buf][wv] = pk; slotx[buf][wv] = cxw; sloty[buf][wv] = cyw;
    }
    __syncthreads();
    // all threads combine the 4 wave winners identically
    u64 wp = slotp[buf][0];
    float nx = slotx[buf][0], ny = sloty[buf][0];
#pragma unroll
    for (int w = 1; w < 4; ++w) {
      u64 op = slotp[buf][w];
      if (op > wp) { wp = op; nx = slotx[buf][w]; ny = sloty[buf][w]; }
    }
    cx = nx; cy = ny;
    if (tid == 0) { histx[it] = nx; histy[it] = ny; }
  }
  __syncthreads();
  {
    float2 o2; o2.x = histx[tid]; o2.y = histy[tid];
    *(float2*)&nxyz[(b * Pn + tid) * 2] = o2;
    *(float2*)&out[(b * Pn + tid) * 2] = o2;
  }
}

// =====================================================================
// Ball query — round 7 verbatim (proven).
// =====================================================================
__global__ __launch_bounds__(256) void k_ballq(
    const float* __restrict__ votes, const float* __restrict__ nxyz,
    int* __restrict__ gidx)
{
  const int bp = blockIdx.x, tid = threadIdx.x;
  const int b = bp >> 8;
  const float* vb = votes + b * Mn * 2;
  const float sx = nxyz[bp * 2], sy = nxyz[bp * 2 + 1];
  const float a = sx * sx + sy * sy;
  float d2[32];
#pragma unroll
  for (int s = 0; s < 32; ++s) {
    int i = tid * 32 + s;
    float x = vb[i * 2], y = vb[i * 2 + 1];
    d2[s] = (a + (x * x + y * y)) - 2.f * (sx * x + sy * y);
  }
  __shared__ float sd[4];
  __shared__ int si[4];
  __shared__ int swi;
  unsigned mask = 0;
  for (int kk = 0; kk < Kn; ++kk) {
    float bd = 3.4e38f; int bi = 0x7fffffff;
#pragma unroll
    for (int s = 0; s < 32; ++s)
      if (!((mask >> s) & 1u) && d2[s] < bd) { bd = d2[s]; bi = tid * 32 + s; }
#pragma unroll
    for (int off = 32; off > 0; off >>= 1) {
      float od = __shfl_xor(bd, off);
      int oi = __shfl_xor(bi, off);
      if (od < bd || (od == bd && oi < bi)) { bd = od; bi = oi; }
    }
    if ((tid & 63) == 0) { sd[tid >> 6] = bd; si[tid >> 6] = bi; }
    __syncthreads();
    if (tid == 0) {
#pragma unroll
      for (int w = 1; w < 4; ++w)
        if (sd[w] < bd || (sd[w] == bd && si[w] < bi)) { bd = sd[w]; bi = si[w]; }
      swi = bi;
      gidx[bp * Kn + kk] = (bd > R2) ? 0 : bi;
    }
    __syncthreads();
    int wi = swi;
    if ((wi >> 5) == tid) mask |= 1u << (wi & 31);
  }
}

// =====================================================================
// Prep: bf16 weight conversions (after the discrete path).
// =====================================================================
__global__ __launch_bounds__(256) void k_prep(
    const float* __restrict__ fw1, const float* __restrict__ fw2,
    const float* __restrict__ aw1, const float* __restrict__ aw2,
    u16* __restrict__ FW1h, u16* __restrict__ FW2b,
    u16* __restrict__ AW1b, u16* __restrict__ AW2b)
{
  const int gid = blockIdx.x * 256 + threadIdx.x;
  const int gsz = gridDim.x * 256;
  for (int i = gid; i < 65536; i += gsz) FW1h[i] = f2bf(fw1[i]);
  for (int i = gid; i < 32768; i += gsz) FW2b[i] = f2bf(fw2[i]);
  for (int i = gid; i < 65536; i += gsz) AW2b[i] = f2bf(aw2[i]);
  for (int i = gid; i < 49152; i += gsz) {
    int o = i / 192, k = i % 192;
    AW1b[i] = (k < 130) ? f2bf(aw1[o * 130 + k]) : (u16)0;
  }
}

// =====================================================================
// k_vf — round 7 verbatim (proven).
// =====================================================================
__global__ __launch_bounds__(256) void k_vf(
    const float* __restrict__ sfeat, const u16* __restrict__ FW1h,
    const float* __restrict__ fb1, const float* __restrict__ fs1,
    const float* __restrict__ ft1, const u16* __restrict__ FW2b,
    const float* __restrict__ fb2, u16* __restrict__ vfeat)
{
  __shared__ u16 Hs[128 * 136];
  __shared__ u16 As[128 * 40];
  __shared__ u16 Bs[128 * 40];
  const int tid = threadIdx.x;
  const int row0 = blockIdx.x * 128;
  const int wid = tid >> 6, lane = tid & 63, m16 = lane & 15, quad = lane >> 4;
  const int wr = wid >> 1, wc = wid & 1;
  const int sr = tid >> 1, sk = (tid & 1) * 16;

  f32x4 acc2[4][4];
#pragma unroll
  for (int mt = 0; mt < 4; ++mt)
#pragma unroll
    for (int nt = 0; nt < 4; ++nt) acc2[mt][nt] = (f32x4){0.f, 0.f, 0.f, 0.f};

  for (int h = 0; h < 2; ++h) {
    f32x4 acc[4][4];
#pragma unroll
    for (int mt = 0; mt < 4; ++mt)
#pragma unroll
      for (int nt = 0; nt < 4; ++nt) acc[mt][nt] = (f32x4){0.f, 0.f, 0.f, 0.f};

    for (int s = 0; s < 8; ++s) {
      __syncthreads();
      {
        const float* src = &sfeat[(row0 + sr) * 256 + s * 32 + sk];
        u32 packed[8];
#pragma unroll
        for (int q = 0; q < 4; ++q) {
          float4 v = *(const float4*)&src[q * 4];
          packed[q * 2]     = (u32)f2bf(v.x) | ((u32)f2bf(v.y) << 16);
          packed[q * 2 + 1] = (u32)f2bf(v.z) | ((u32)f2bf(v.w) << 16);
        }
        *(uint4*)&As[sr * 40 + sk]     = *(uint4*)&packed[0];
        *(uint4*)&As[sr * 40 + sk + 8] = *(uint4*)&packed[4];
        const u16* bsrc = &FW1h[(h * 128 + sr) * 256 + s * 32 + sk];
        *(uint4*)&Bs[sr * 40 + sk]     = *(const uint4*)&bsrc[0];
        *(uint4*)&Bs[sr * 40 + sk + 8] = *(const uint4*)&bsrc[8];
      }
      __syncthreads();
#pragma unroll
      for (int mt = 0; mt < 4; ++mt) {
        bf16x8 af = *(const bf16x8*)&As[(wr * 64 + mt * 16 + m16) * 40 + quad * 8];
#pragma unroll
        for (int nt = 0; nt < 4; ++nt) {
          bf16x8 bfr = *(const bf16x8*)&Bs[(wc * 64 + nt * 16 + m16) * 40 + quad * 8];
          acc[mt][nt] = __builtin_amdgcn_mfma_f32_16x16x32_bf16(af, bfr, acc[mt][nt], 0, 0, 0);
        }
      }
    }
    __syncthreads();
#pragma unroll
    for (int nt = 0; nt < 4; ++nt) {
      int colL = wc * 64 + nt * 16 + m16;
      int col = h * 128 + colL;
      float bb = fb1[col], ss = fs1[col], tt = ft1[col];
#pragma unroll
      for (int mt = 0; mt < 4; ++mt) {
        int rL = wr * 64 + mt * 16 + quad * 4;
#pragma unroll
        for (int r = 0; r < 4; ++r)
          Hs[(rL + r) * 136 + colL] = f2bf(fmaxf((acc[mt][nt][r] + bb) * ss + tt, 0.f));
      }
    }
    for (int s2 = 0; s2 < 4; ++s2) {
      __syncthreads();
      {
        const u16* bsrc = &FW2b[sr * 256 + h * 128 + s2 * 32 + sk];
        *(uint4*)&Bs[sr * 40 + sk]     = *(const uint4*)&bsrc[0];
        *(uint4*)&Bs[sr * 40 + sk + 8] = *(const uint4*)&bsrc[8];
      }
      __syncthreads();
#pragma unroll
      for (int mt = 0; mt < 4; ++mt) {
        bf16x8 af = *(const bf16x8*)&Hs[(wr * 64 + mt * 16 + m16) * 136 + s2 * 32 + quad * 8];
#pragma unroll
        for (int nt = 0; nt < 4; ++nt) {
          bf16x8 bfr = *(const bf16x8*)&Bs[(wc * 64 + nt * 16 + m16) * 40 + quad * 8];
          acc2[mt][nt] = __builtin_amdgcn_mfma_f32_16x16x32_bf16(af, bfr, acc2[mt][nt], 0, 0, 0);
        }
      }
    }
  }
#pragma unroll
  for (int nt = 0; nt < 4; ++nt) {
    int col = wc * 64 + nt * 16 + m16;
    float bb = fb2[col];
#pragma unroll
    for (int mt = 0; mt < 4; ++mt) {
      int rbase = row0 + wr * 64 + mt * 16 + quad * 4;
#pragma unroll
      for (int r = 0; r < 4; ++r)
        vfeat[(rbase + r) * 128 + col] = f2bf(acc2[mt][nt][r] + bb);
    }
  }
}

// =====================================================================
// k_agg — round 7 verbatim (proven).
// =====================================================================
__global__ __launch_bounds__(256) void k_agg(
    const float* __restrict__ votes, const u16* __restrict__ vfeat,
    const float* __restrict__ nxyz, const int* __restrict__ gidx,
    const u16* __restrict__ AW1b, const float* __restrict__ ab1,
    const float* __restrict__ as1, const float* __restrict__ at1,
    const u16* __restrict__ AW2b, const float* __restrict__ ab2,
    const float* __restrict__ as2, const float* __restrict__ at2,
    float* __restrict__ pooled)
{
  __shared__ u16 U[32 * 264];
  __shared__ u16 Bs[256 * 72];
  __shared__ int gix[32];
  __shared__ float gvx[32], gvy[32];
  u16* CombA = U;
  u16* As = U;
  float* x2T = (float*)Bs;

  const int bp = blockIdx.x, tid = threadIdx.x, b = bp >> 8;
  if (tid < 32) {
    int g = gidx[bp * 32 + tid];
    gix[tid] = g;
    gvx[tid] = votes[(b * Mn + g) * 2];
    gvy[tid] = votes[(b * Mn + g) * 2 + 1];
  }
  __syncthreads();
  const float sx = nxyz[bp * 2], sy = nxyz[bp * 2 + 1];

  if (tid < 192) {
    int row = tid / 6, c = tid % 6;
    const u16* vsrc = &vfeat[(b * Mn + gix[row]) * 128];
    u16* dst = &CombA[row * 200 + c * 32];
    if (c == 0) {
      dst[0] = f2bf(gvx[row] - sx);
      dst[1] = f2bf(gvy[row] - sy);
      for (int k = 2; k < 32; ++k) dst[k] = vsrc[k - 2];
    } else if (c <= 3) {
      for (int k = 0; k < 32; ++k) dst[k] = vsrc[c * 32 + k - 2];
    } else if (c == 4) {
      dst[0] = vsrc[126]; dst[1] = vsrc[127];
      for (int k = 2; k < 32; ++k) dst[k] = 0;
    } else {
      for (int k = 0; k < 32; ++k) dst[k] = 0;
    }
  }

  const int wid = tid >> 6, lane = tid & 63, m16 = lane & 15, quad = lane >> 4;
  const int mt = wid & 1, nh = wid >> 1;

  f32x4 acc[8];
#pragma unroll
  for (int nt = 0; nt < 8; ++nt) acc[nt] = (f32x4){0.f, 0.f, 0.f, 0.f};
  for (int s = 0; s < 3; ++s) {
    __syncthreads();
    for (int i = tid; i < 4096; i += 256) {
      int n = i >> 4, c4 = i & 15;
      *(uint2*)&Bs[n * 72 + c4 * 4] = *(const uint2*)&AW1b[n * 192 + s * 64 + c4 * 4];
    }
    __syncthreads();
#pragma unroll
    for (int ks = 0; ks < 2; ++ks) {
      bf16x8 af = *(const bf16x8*)&CombA[(mt * 16 + m16) * 200 + s * 64 + ks * 32 + quad * 8];
#pragma unroll
      for (int nt = 0; nt < 8; ++nt) {
        bf16x8 bf_ = *(const bf16x8*)&Bs[(nh * 128 + nt * 16 + m16) * 72 + ks * 32 + quad * 8];
        acc[nt] = __builtin_amdgcn_mfma_f32_16x16x32_bf16(af, bf_, acc[nt], 0, 0, 0);
      }
    }
  }
  __syncthreads();
#pragma unroll
  for (int nt = 0; nt < 8; ++nt) {
    int col = nh * 128 + nt * 16 + m16;
    float bb = ab1[col], ss = as1[col], tt = at1[col];
#pragma unroll
    for (int r = 0; r < 4; ++r) {
      int samp = mt * 16 + quad * 4 + r;
      As[samp * 264 + col] = f2bf(fmaxf((acc[nt][r] + bb) * ss + tt, 0.f));
    }
  }

  f32x4 acc2[8];
#pragma unroll
  for (int nt = 0; nt < 8; ++nt) acc2[nt] = (f32x4){0.f, 0.f, 0.f, 0.f};
  for (int s = 0; s < 4; ++s) {
    __syncthreads();
    for (int i = tid; i < 4096; i += 256) {
      int n = i >> 4, c4 = i & 15;
      *(uint2*)&Bs[n * 72 + c4 * 4] = *(const uint2*)&AW2b[n * 256 + s * 64 + c4 * 4];
    }
    __syncthreads();
#pragma unroll
    for (int ks = 0; ks < 2; ++ks) {
      bf16x8 af = *(const bf16x8*)&As[(mt * 16 + m16) * 264 + s * 64 + ks * 32 + quad * 8];
#pragma unroll
      for (int nt = 0; nt < 8; ++nt) {
        bf16x8 bf_ = *(const bf16x8*)&Bs[(nh * 128 + nt * 16 + m16) * 72 + ks * 32 + quad * 8];
        acc2[nt] = __builtin_amdgcn_mfma_f32_16x16x32_bf16(af, bf_, acc2[nt], 0, 0, 0);
      }
    }
  }
  __syncthreads();
#pragma unroll
  for (int nt = 0; nt < 8; ++nt) {
    int col = nh * 128 + nt * 16 + m16;
    float bb = ab2[col], ss = as2[col], tt = at2[col];
#pragma unroll
    for (int r = 0; r < 4; ++r) {
      int samp = mt * 16 + quad * 4 + r;
      x2T[col * 33 + samp] = fmaxf((acc2[nt][r] + bb) * ss + tt, 0.f);
    }
  }
  __syncthreads();
  {
    float m = x2T[tid * 33];
#pragma unroll
    for (int s2 = 1; s2 < 32; ++s2) m = fmaxf(m, x2T[tid * 33 + s2]);
    pooled[bp * 256 + tid] = m;
  }
}

// =====================================================================
// Proposal head — round 7 verbatim (proven).
// =====================================================================
__global__ __launch_bounds__(256) void k_head(
    const float* __restrict__ pooled,
    const float* __restrict__ pw1, const float* __restrict__ pb1,
    const float* __restrict__ ps1, const float* __restrict__ pt1,
    const float* __restrict__ pw2, const float* __restrict__ pb2,
    const float* __restrict__ ps2, const float* __restrict__ pt2,
    const float* __restrict__ objw, const float* __restrict__ objb,
    const float* __restrict__ clsw, const float* __restrict__ clsb,
    float* __restrict__ out)
{
  __shared__ float xr[256], y1[256], y2[128];
  const int bp = blockIdx.x, tid = threadIdx.x;
  xr[tid] = pooled[bp * 256 + tid];
  __syncthreads();
  {
    float a = 0.f;
    for (int c = 0; c < 256; ++c) a = fmaf(xr[c], pw1[tid * 256 + c], a);
    a = (a + pb1[tid]) * ps1[tid] + pt1[tid];
    y1[tid] = fmaxf(a, 0.f);
  }
  __syncthreads();
  if (tid < 128) {
    float a = 0.f;
    for (int c = 0; c < 256; ++c) a = fmaf(y1[c], pw2[tid * 256 + c], a);
    a = (a + pb2[tid]) * ps2[tid] + pt2[tid];
    y2[tid] = fmaxf(a, 0.f);
  }
  __syncthreads();
  if (tid < 10) {
    float a = 0.f;
    for (int c = 0; c < 128; ++c) a = fmaf(y2[c], clsw[tid * 128 + c], a);
    out[6144 + bp * 10 + tid] = a + clsb[tid];
  } else if (tid == 10) {
    float a = 0.f;
    for (int c = 0; c < 128; ++c) a = fmaf(y2[c], objw[c], a);
    out[4096 + bp] = a + objb[0];
  }
}

// =====================================================================
extern "C" void kernel_launch(void* const* d_in, const int* in_sizes, int n_in,
                              void* d_out, int out_size, void* d_ws, size_t ws_size,
                              hipStream_t stream)
{
  (void)in_sizes; (void)n_in; (void)out_size; (void)ws_size;
  const float* sxyz  = (const float*)d_in[0];
  const float* sfeat = (const float*)d_in[1];
  const float* ow1 = (const float*)d_in[2];
  const float* ob1 = (const float*)d_in[3];
  const float* os1 = (const float*)d_in[4];
  const float* ot1 = (const float*)d_in[5];
  const float* ow2 = (const float*)d_in[6];
  const float* ob2 = (const float*)d_in[7];
  const float* fw1 = (const float*)d_in[8];
  const float* fb1 = (const float*)d_in[9];
  const float* fs1 = (const float*)d_in[10];
  const float* ft1 = (const float*)d_in[11];
  const float* fw2 = (const float*)d_in[12];
  const float* fb2 = (const float*)d_in[13];
  const float* aw1 = (const float*)d_in[14];
  const float* ab1 = (const float*)d_in[15];
  const float* as1 = (const float*)d_in[16];
  const float* at1 = (const float*)d_in[17];
  const float* aw2 = (const float*)d_in[18];
  const float* ab2 = (const float*)d_in[19];
  const float* as2 = (const float*)d_in[20];
  const float* at2 = (const float*)d_in[21];
  const float* pw1 = (const float*)d_in[22];
  const float* pb1 = (const float*)d_in[23];
  const float* ps1 = (const float*)d_in[24];
  const float* pt1 = (const float*)d_in[25];
  const float* pw2 = (const float*)d_in[26];
  const float* pb2 = (const float*)d_in[27];
  const float* ps2 = (const float*)d_in[28];
  const float* pt2 = (const float*)d_in[29];
  const float* objw = (const float*)d_in[30];
  const float* objb = (const float*)d_in[31];
  const float* clsw = (const float*)d_in[32];
  const float* clsb = (const float*)d_in[33];

  char* ws = (char*)d_ws;
  float* votes  = (float*)(ws + 0);             //    524,288
  u16*   vfeat  = (u16*)  (ws + 524288);        // 16,777,216
  float* nxyz   = (float*)(ws + 17301504);      //     16,384
  int*   gidxp  = (int*)  (ws + 17317888);      //    262,144
  float* pooled = (float*)(ws + 17580032);      //  2,097,152
  u16*   FW1h   = (u16*)  (ws + 19677184);      //    131,072
  u16*   FW2b   = (u16*)  (ws + 19808256);      //     65,536
  u16*   AW1b   = (u16*)  (ws + 19873792);      //     98,304
  u16*   AW2b   = (u16*)  (ws + 19972096);      //    131,072
  float* out    = (float*)d_out;

  k_voting_off<<<dim3(4096), dim3(256), 0, stream>>>(
      sxyz, sfeat, ow1, ob1, os1, ot1, ow2, ob2, votes);

  k_fps<<<dim3(8), dim3(256), 0, stream>>>(votes, nxyz, out);

  k_ballq<<<dim3(2048), dim3(256), 0, stream>>>(votes, nxyz, gidxp);

  k_prep<<<dim3(256), dim3(256), 0, stream>>>(
      fw1, fw2, aw1, aw2, FW1h, FW2b, AW1b, AW2b);

  k_vf<<<dim3(512), dim3(256), 0, stream>>>(
      sfeat, FW1h, fb1, fs1, ft1, FW2b, fb2, vfeat);

  k_agg<<<dim3(2048), dim3(256), 0, stream>>>(
      votes, vfeat, nxyz, gidxp, AW1b, ab1, as1, at1,
      AW2b, ab2, as2, at2, pooled);

  k_head<<<dim3(2048), dim3(256), 0, stream>>>(
      pooled, pw1, pb1, ps1, pt1, pw2, pb2, ps2, pt2,
      objw, objb, clsw, clsb, out);
}